// Round 1
// baseline (134.458 us; speedup 1.0000x reference)
//
#include <hip/hip_runtime.h>
#include <stdint.h>

#define KWORDS 128   // 4096 bits / 32 per row

// ---------------- pack kernels ----------------
// Convention: word w of a row holds elements [32w, 32w+31], element e at bit (e&31).
// __ballot across 64 lanes (lane i's pred at bit i) matches this when lanes map
// 1:1 to consecutive elements and the wave base is 64-aligned.

__global__ void pack_f32(const float* __restrict__ in, uint32_t* __restrict__ out) {
    int gtid = blockIdx.x * blockDim.x + threadIdx.x;
    bool pred = in[gtid] >= 0.0f;
    unsigned long long m = __ballot(pred);
    if ((threadIdx.x & 63) == 0) {
        int wbase = gtid >> 5;          // gtid is 64-aligned here
        out[wbase]     = (uint32_t)m;
        out[wbase + 1] = (uint32_t)(m >> 32);
    }
}

__global__ void pack_i32(const int* __restrict__ in, uint32_t* __restrict__ out) {
    int gtid = blockIdx.x * blockDim.x + threadIdx.x;
    bool pred = in[gtid] != 0;
    unsigned long long m = __ballot(pred);
    if ((threadIdx.x & 63) == 0) {
        int wbase = gtid >> 5;
        out[wbase]     = (uint32_t)m;
        out[wbase + 1] = (uint32_t)(m >> 32);
    }
}

// ---------------- popcount GEMM ----------------
// C[b,n] = 4096 - sum_w popc(A[b,w] ^ W[n,w]); A: Mx128 words, W: Nx128 words.
// PACK_OUT: emit bit (match >= thr) packed into Mx(N/32) words (layer 1).
// else:     emit int32 match counts (layer 2, final output).

template<bool PACK_OUT>
__global__ __launch_bounds__(256)
void bnn_gemm(const uint32_t* __restrict__ A,
              const uint32_t* __restrict__ W,
              int N,
              const int* __restrict__ thr_ptr,
              uint32_t* __restrict__ out_pack,
              int* __restrict__ out_i32)
{
    constexpr int BM = 64, BN = 64, CK = 32;   // tile rows/cols, K-chunk words
    constexpr int LDT = 36;                    // padded LDS stride (words): 144B, 16B-aligned
    __shared__ uint32_t a_tile[BM * LDT];
    __shared__ uint32_t w_tile[BN * LDT];

    const int tid = threadIdx.x;
    const int th  = tid & 15;    // h-group: cols th + 16j
    const int tb  = tid >> 4;    // b-group: rows tb*4 + i
    const int bm  = blockIdx.y;
    const int bn  = blockIdx.x;

    const uint32_t* Ab = A + (size_t)(bm * BM) * KWORDS;
    const uint32_t* Wb = W + (size_t)(bn * BN) * KWORDS;

    int acc[4][4] = {};

    for (int ck = 0; ck < KWORDS / CK; ++ck) {
        // stage 64 rows x 32 words per tile: 512 quads, 256 threads x 2 quads each
        #pragma unroll
        for (int it = 0; it < 2; ++it) {
            int q   = tid + it * 256;
            int row = q >> 3;
            int qc  = q & 7;
            uint4 av = *(const uint4*)(Ab + (size_t)row * KWORDS + ck * CK + qc * 4);
            uint4 wv = *(const uint4*)(Wb + (size_t)row * KWORDS + ck * CK + qc * 4);
            *(uint4*)(a_tile + row * LDT + qc * 4) = av;
            *(uint4*)(w_tile + row * LDT + qc * 4) = wv;
        }
        __syncthreads();

        #pragma unroll
        for (int kw4 = 0; kw4 < CK / 4; ++kw4) {
            uint4 a4[4], w4[4];
            #pragma unroll
            for (int i = 0; i < 4; ++i)
                a4[i] = *(const uint4*)(a_tile + (tb * 4 + i) * LDT + kw4 * 4);
            #pragma unroll
            for (int j = 0; j < 4; ++j)
                w4[j] = *(const uint4*)(w_tile + (th + 16 * j) * LDT + kw4 * 4);
            #pragma unroll
            for (int i = 0; i < 4; ++i)
                #pragma unroll
                for (int j = 0; j < 4; ++j) {
                    acc[i][j] += __popc(a4[i].x ^ w4[j].x);
                    acc[i][j] += __popc(a4[i].y ^ w4[j].y);
                    acc[i][j] += __popc(a4[i].z ^ w4[j].z);
                    acc[i][j] += __popc(a4[i].w ^ w4[j].w);
                }
        }
        __syncthreads();
    }

    if constexpr (PACK_OUT) {
        const int thr = *thr_ptr;
        uint8_t* bits = (uint8_t*)a_tile;   // reuse: 64x64 bytes = 4KB (< 9216)
        #pragma unroll
        for (int i = 0; i < 4; ++i)
            #pragma unroll
            for (int j = 0; j < 4; ++j) {
                int match = 4096 - acc[i][j];
                bits[(tb * 4 + i) * 64 + (th + 16 * j)] = (match >= thr) ? 1 : 0;
            }
        __syncthreads();
        if (tid < 128) {
            int r = tid >> 1, ws = tid & 1;
            uint32_t word = 0;
            #pragma unroll
            for (int k = 0; k < 32; ++k)
                word |= (uint32_t)(bits[r * 64 + ws * 32 + k] & 1) << k;
            out_pack[(size_t)(bm * BM + r) * (N >> 5) + bn * 2 + ws] = word;
        }
    } else {
        #pragma unroll
        for (int i = 0; i < 4; ++i) {
            int b = bm * BM + tb * 4 + i;
            #pragma unroll
            for (int j = 0; j < 4; ++j) {
                int h = bn * BN + th + 16 * j;
                out_i32[(size_t)b * N + h] = 4096 - acc[i][j];
            }
        }
    }
}

extern "C" void kernel_launch(void* const* d_in, const int* in_sizes, int n_in,
                              void* d_out, int out_size, void* d_ws, size_t ws_size,
                              hipStream_t stream) {
    const float* x   = (const float*)d_in[0];
    const int*   w1  = (const int*)d_in[1];
    const int*   w2  = (const int*)d_in[2];
    const int*   thr = (const int*)d_in[3];
    int* out = (int*)d_out;

    const int B = 2048, IN = 4096, H = 4096, OUT = 1024;

    uint8_t* ws = (uint8_t*)d_ws;
    uint32_t* xpack   = (uint32_t*)(ws);                 // B  *128 w = 1.0 MB
    uint32_t* w1pack  = (uint32_t*)(ws + (1u << 20));    // H  *128 w = 2.0 MB
    uint32_t* w2pack  = (uint32_t*)(ws + (3u << 20));    // OUT*128 w = 0.5 MB
    uint32_t* actpack = (uint32_t*)(ws + (7u << 19));    // B  *128 w = 1.0 MB

    pack_f32<<<B * IN  / 256, 256, 0, stream>>>(x,  xpack);
    pack_i32<<<H * IN  / 256, 256, 0, stream>>>(w1, w1pack);
    pack_i32<<<OUT * H / 256, 256, 0, stream>>>(w2, w2pack);

    dim3 g1(H / 64, B / 64);
    bnn_gemm<true><<<g1, 256, 0, stream>>>(xpack, w1pack, H, thr, actpack, nullptr);

    dim3 g2(OUT / 64, B / 64);
    bnn_gemm<false><<<g2, 256, 0, stream>>>(actpack, w2pack, OUT, nullptr, nullptr, out);
}

// Round 2
// 127.555 us; speedup vs baseline: 1.0541x; 1.0541x over previous
//
#include <hip/hip_runtime.h>
#include <stdint.h>

#define KWORDS 128   // 4096 bits / 32 per row

// quad swizzle within a 64B row: spreads rows {r, r+8, r+16, r+24} across
// distinct bank-quads -> a-reads conflict-free, w-reads 2-way (free).
__device__ __forceinline__ uint32_t swz(int row) {
    return (uint32_t)(((row >> 1) ^ (row >> 3)) & 3);
}

// fused popcount-accumulate: acc = popc(a^w) + acc  (v_bcnt_u32_b32 D,S0,S1)
__device__ __forceinline__ void xpc(int& acc, uint32_t a, uint32_t w) {
    uint32_t x = a ^ w;
    asm("v_bcnt_u32_b32 %0, %1, %0" : "+v"(acc) : "v"(x));
}

// ---------------- pack kernels: 1 output word (32 elems) per thread ----------
__global__ __launch_bounds__(256)
void pack_f32_k(const float* __restrict__ in, uint32_t* __restrict__ out) {
    size_t t = (size_t)blockIdx.x * 256 + threadIdx.x;
    const float4* p = (const float4*)(in + t * 32);
    uint32_t w = 0;
    #pragma unroll
    for (int q = 0; q < 8; ++q) {
        float4 v = p[q];
        w |= (v.x >= 0.0f ? 1u : 0u) << (4*q + 0);
        w |= (v.y >= 0.0f ? 1u : 0u) << (4*q + 1);
        w |= (v.z >= 0.0f ? 1u : 0u) << (4*q + 2);
        w |= (v.w >= 0.0f ? 1u : 0u) << (4*q + 3);
    }
    out[t] = w;
}

__global__ __launch_bounds__(256)
void pack_i32_k(const int* __restrict__ in, uint32_t* __restrict__ out) {
    size_t t = (size_t)blockIdx.x * 256 + threadIdx.x;
    const int4* p = (const int4*)(in + t * 32);
    uint32_t w = 0;
    #pragma unroll
    for (int q = 0; q < 8; ++q) {
        int4 v = p[q];   // values in {0,1}
        w |= (uint32_t)(v.x & 1) << (4*q + 0);
        w |= (uint32_t)(v.y & 1) << (4*q + 1);
        w |= (uint32_t)(v.z & 1) << (4*q + 2);
        w |= (uint32_t)(v.w & 1) << (4*q + 3);
    }
    out[t] = w;
}

// ---------------- popcount GEMM ----------------
// C[b,n] = 4096 - sum_w popc(A[b,w] ^ W[n,w]); A: Mx128 words, W: Nx128 words.
// BM=128 rows, BN cols (128 for L1, 64 for L2), 256 threads, 8xNJ regs/thread.
// PACK_OUT: emit bit (match >= thr) packed into Mx(N/32) words (layer 1).

template<int BN, int NJ, bool PACK_OUT>
__global__ __launch_bounds__(256, 2)
void bnn_gemm(const uint32_t* __restrict__ A,
              const uint32_t* __restrict__ W,
              int N,
              const int* __restrict__ thr_ptr,
              uint32_t* __restrict__ out_pack,
              int* __restrict__ out_i32)
{
    constexpr int BM   = 128;
    constexpr int CK   = 16;               // words per K-chunk (64B per row)
    constexpr int NCH  = KWORDS / CK;      // 8 chunks
    constexpr int ROWS = BM + BN;          // staged rows (A then W)
    constexpr int NIT  = (ROWS * 4) / 256; // quads per thread per chunk (exact)

    __shared__ uint32_t lds[ROWS * CK];    // 64B/row, quad-swizzled

    const int tid = threadIdx.x;
    const int th  = tid & 15;              // cols th + 16*j
    const int tb  = tid >> 4;              // rows tb*8 + i
    const int bm  = blockIdx.y;
    const int bn  = blockIdx.x;

    const uint32_t* Ab = A + (size_t)(bm * BM) * KWORDS;
    const uint32_t* Wb = W + (size_t)(bn * BN) * KWORDS;

    int acc[8][NJ];
    #pragma unroll
    for (int i = 0; i < 8; ++i)
        #pragma unroll
        for (int j = 0; j < NJ; ++j) acc[i][j] = 0;

    // precomputed swizzled LDS read bases (byte offsets); quad kw4 at base^(kw4<<4)
    uint32_t abase[8], wbase[NJ];
    #pragma unroll
    for (int i = 0; i < 8; ++i) {
        int r = tb * 8 + i;
        abase[i] = (uint32_t)(r * 64) | (swz(r) << 4);
    }
    #pragma unroll
    for (int j = 0; j < NJ; ++j) {
        int r = th + 16 * j;
        wbase[j] = (uint32_t)((BM + r) * 64) | (swz(r) << 4);
    }

    uint4 pre[NIT];

    auto ldchunk = [&](int ck) {
        #pragma unroll
        for (int it = 0; it < NIT; ++it) {
            int idx = tid + 256 * it;
            int row = idx >> 2, q = idx & 3;
            const uint32_t* src = (row < BM)
                ? (Ab + (size_t)row * KWORDS)
                : (Wb + (size_t)(row - BM) * KWORDS);
            pre[it] = *(const uint4*)(src + ck * CK + q * 4);
        }
    };
    auto wrchunk = [&]() {
        #pragma unroll
        for (int it = 0; it < NIT; ++it) {
            int idx = tid + 256 * it;
            int row = idx >> 2, q = idx & 3;   // swz(row)==swz(row-BM) since BM=128
            *(uint4*)((char*)lds + row * 64 + (((uint32_t)q ^ swz(row)) << 4)) = pre[it];
        }
    };

    ldchunk(0);
    wrchunk();
    __syncthreads();

    for (int ck = 0; ck < NCH; ++ck) {
        if (ck + 1 < NCH) ldchunk(ck + 1);   // T14: issue loads, consume after barrier

        #pragma unroll
        for (int kw4 = 0; kw4 < 4; ++kw4) {
            uint4 a4[8], w4[NJ];
            #pragma unroll
            for (int i = 0; i < 8; ++i)
                a4[i] = *(const uint4*)((char*)lds + (abase[i] ^ (uint32_t)(kw4 << 4)));
            #pragma unroll
            for (int j = 0; j < NJ; ++j)
                w4[j] = *(const uint4*)((char*)lds + (wbase[j] ^ (uint32_t)(kw4 << 4)));
            #pragma unroll
            for (int i = 0; i < 8; ++i)
                #pragma unroll
                for (int j = 0; j < NJ; ++j) {
                    xpc(acc[i][j], a4[i].x, w4[j].x);
                    xpc(acc[i][j], a4[i].y, w4[j].y);
                    xpc(acc[i][j], a4[i].z, w4[j].z);
                    xpc(acc[i][j], a4[i].w, w4[j].w);
                }
        }
        __syncthreads();
        if (ck + 1 < NCH) {
            wrchunk();
            __syncthreads();
        }
    }

    if constexpr (PACK_OUT) {
        const int thr = *thr_ptr;
        uint8_t* bits = (uint8_t*)lds;       // BM*BN = 16384 B == sizeof(lds)
        #pragma unroll
        for (int i = 0; i < 8; ++i)
            #pragma unroll
            for (int j = 0; j < NJ; ++j) {
                int match = 4096 - acc[i][j];
                bits[(tb * 8 + i) * BN + th + 16 * j] = (match >= thr) ? 1 : 0;
            }
        __syncthreads();
        // pack 128 rows x 4 words; 512 words, 2 per thread
        #pragma unroll
        for (int it = 0; it < 2; ++it) {
            int idx = tid + it * 256;
            int row = idx >> 2, wq = idx & 3;
            const uint32_t* p = (const uint32_t*)(bits + row * BN + wq * 32);
            uint32_t word = 0;
            #pragma unroll
            for (int m = 0; m < 8; ++m) {
                uint32_t v = p[m] & 0x01010101u;
                word |= (((v * 0x01020408u) >> 24) & 0xFu) << (4 * m);
            }
            out_pack[(size_t)(bm * BM + row) * (N >> 5) + bn * 4 + wq] = word;
        }
    } else {
        #pragma unroll
        for (int i = 0; i < 8; ++i) {
            int b = bm * BM + tb * 8 + i;
            #pragma unroll
            for (int j = 0; j < NJ; ++j) {
                int h = bn * BN + th + 16 * j;
                out_i32[(size_t)b * N + h] = 4096 - acc[i][j];
            }
        }
    }
}

extern "C" void kernel_launch(void* const* d_in, const int* in_sizes, int n_in,
                              void* d_out, int out_size, void* d_ws, size_t ws_size,
                              hipStream_t stream) {
    const float* x   = (const float*)d_in[0];
    const int*   w1  = (const int*)d_in[1];
    const int*   w2  = (const int*)d_in[2];
    const int*   thr = (const int*)d_in[3];
    int* out = (int*)d_out;

    const int B = 2048, IN = 4096, H = 4096, OUT = 1024;

    uint8_t* ws = (uint8_t*)d_ws;
    uint32_t* xpack   = (uint32_t*)(ws);                 // B  *128 w = 1.0 MB
    uint32_t* w1pack  = (uint32_t*)(ws + (1u << 20));    // H  *128 w = 2.0 MB
    uint32_t* w2pack  = (uint32_t*)(ws + (3u << 20));    // OUT*128 w = 0.5 MB
    uint32_t* actpack = (uint32_t*)(ws + (7u << 19));    // B  *128 w = 1.0 MB

    pack_f32_k<<<B * IN  / 32 / 256, 256, 0, stream>>>(x,  xpack);
    pack_i32_k<<<H * IN  / 32 / 256, 256, 0, stream>>>(w1, w1pack);
    pack_i32_k<<<OUT * H / 32 / 256, 256, 0, stream>>>(w2, w2pack);

    dim3 g1(H / 128, B / 128);   // 32 x 16 = 512 blocks
    bnn_gemm<128, 8, true><<<g1, 256, 0, stream>>>(xpack, w1pack, H, thr, actpack, nullptr);

    dim3 g2(OUT / 64, B / 128);  // 16 x 16 = 256 blocks
    bnn_gemm<64, 4, false><<<g2, 256, 0, stream>>>(actpack, w2pack, OUT, nullptr, nullptr, out);
}